// Round 1
// baseline (264.148 us; speedup 1.0000x reference)
//
#include <hip/hip_runtime.h>

// Problem constants (fixed by setup_inputs in the reference)
constexpr int B = 128;
constexpr int C = 4;          // classes; C*S = 2^18
constexpr int S = 65536;      // 2^16
constexpr int N = B * S;      // 8388608 positions
constexpr int NG = N / 4;     // float4 groups
constexpr int NSEG = 8;
// ws layout: acc[0..7] = per-segment sum(loss), acc[8..15] = per-segment count(valid),
//            acc[16] = sum(mask)
constexpr int NACC = 2 * NSEG + 1;  // 17

__global__ __launch_bounds__(256) void ce_partial_kernel(
    const float* __restrict__ input,   // (B, C, S)
    const int*   __restrict__ target,  // (B, S) values in [0, C)
    const int*   __restrict__ seg,     // (B, S) values in [0, NSEG)
    const float* __restrict__ mask,    // (B, S) in {0,1}
    float* __restrict__ acc)           // 17 floats, pre-zeroed
{
    float ssum[NSEG], scnt[NSEG];
#pragma unroll
    for (int k = 0; k < NSEG; ++k) { ssum[k] = 0.f; scnt[k] = 0.f; }
    float msum = 0.f;

    const int stride = gridDim.x * blockDim.x;
    for (int g = blockIdx.x * blockDim.x + threadIdx.x; g < NG; g += stride) {
        const int p = g << 2;             // flat position (b*S + s), 4-aligned
        const int b = p >> 16;            // p / S
        const int s = p & (S - 1);
        const int base = (b << 18) + s;   // b*C*S + s

        const float4 l0 = *(const float4*)(input + base);
        const float4 l1 = *(const float4*)(input + base + S);
        const float4 l2 = *(const float4*)(input + base + 2 * S);
        const float4 l3 = *(const float4*)(input + base + 3 * S);
        const int4   tg = *(const int4*)(target + p);
        const int4   sv = *(const int4*)(seg + p);
        const float4 mk = *(const float4*)(mask + p);

        const float a0[4] = { l0.x, l0.y, l0.z, l0.w };
        const float a1[4] = { l1.x, l1.y, l1.z, l1.w };
        const float a2[4] = { l2.x, l2.y, l2.z, l2.w };
        const float a3[4] = { l3.x, l3.y, l3.z, l3.w };
        const int   tgv[4] = { tg.x, tg.y, tg.z, tg.w };
        const int   sgv[4] = { sv.x, sv.y, sv.z, sv.w };
        const float mkv[4] = { mk.x, mk.y, mk.z, mk.w };

#pragma unroll
        for (int j = 0; j < 4; ++j) {
            const float x0 = a0[j], x1 = a1[j], x2 = a2[j], x3 = a3[j];
            const float m = fmaxf(fmaxf(x0, x1), fmaxf(x2, x3));
            const float sum = __expf(x0 - m) + __expf(x1 - m)
                            + __expf(x2 - m) + __expf(x3 - m);
            const float lse = m + __logf(sum);
            const int t = tgv[j];
            const float chosen = (t == 0) ? x0 : (t == 1) ? x1 : (t == 2) ? x2 : x3;
            const float mval = mkv[j];
            const float loss = (lse - chosen) * mval;   // ce * mask
            const float v = (mval > 0.f) ? 1.f : 0.f;   // valid
            const int sgj = sgv[j];
            msum += mval;
            // Predicated accumulation: avoids dynamic register indexing (scratch spill)
#pragma unroll
            for (int k = 0; k < NSEG; ++k) {
                const bool hit = (sgj == k);
                ssum[k] += hit ? loss : 0.f;
                scnt[k] += hit ? v : 0.f;
            }
        }
    }

    // Wave (64-lane) butterfly reduction of all 17 accumulators
    float vals[NACC];
#pragma unroll
    for (int k = 0; k < NSEG; ++k) { vals[k] = ssum[k]; vals[NSEG + k] = scnt[k]; }
    vals[16] = msum;
#pragma unroll
    for (int i = 0; i < NACC; ++i) {
        float v = vals[i];
#pragma unroll
        for (int off = 32; off > 0; off >>= 1)
            v += __shfl_xor(v, off, 64);
        vals[i] = v;
    }

    __shared__ float red[4][NACC];
    const int wave = threadIdx.x >> 6;
    const int lane = threadIdx.x & 63;
    if (lane == 0) {
#pragma unroll
        for (int i = 0; i < NACC; ++i) red[wave][i] = vals[i];
    }
    __syncthreads();
    if (threadIdx.x < NACC) {
        const int i = threadIdx.x;
        const float v = red[0][i] + red[1][i] + red[2][i] + red[3][i];
        atomicAdd(&acc[i], v);   // device-scope by default on gfx950
    }
}

__global__ void ce_final_kernel(const float* __restrict__ acc, float* __restrict__ out)
{
    if (threadIdx.x != 0 || blockIdx.x != 0) return;

    float ssum[NSEG], scnt[NSEG];
    float tot_loss = 0.f;
    for (int k = 0; k < NSEG; ++k) {
        ssum[k] = acc[k];
        scnt[k] = acc[NSEG + k];
        tot_loss += ssum[k];
    }
    const float msum = acc[16];
    const float fallback = tot_loss / (float)N;   // jnp.mean(loss)

    float cl[NSEG], cc[NSEG];
    float total = 0.f;
    for (int k = 0; k < NSEG; ++k) {
        const bool has = scnt[k] > 0.f;
        cl[k] = has ? (ssum[k] / scnt[k]) : fallback;
        cc[k] = has ? scnt[k] : 1.f;
        total += cl[k] * cc[k];
    }
    float num = 0.f;
    for (int k = 0; k < NSEG; ++k) {
        const float prop = (total > 0.f) ? (cl[k] * cc[k] / total) : (1.f / (float)NSEG);
        const float w = 1.f + prop;               // WEIGHT_ALPHA = 1.0
        // sum(loss * adaptive_weights) = sum_k w[k] * seg_sum[k]
        num += w * ssum[k];
    }
    out[0] = num / msum;                          // / sum(mask)
}

extern "C" void kernel_launch(void* const* d_in, const int* in_sizes, int n_in,
                              void* d_out, int out_size, void* d_ws, size_t ws_size,
                              hipStream_t stream) {
    const float* input  = (const float*)d_in[0];
    const int*   target = (const int*)d_in[1];
    const int*   seg    = (const int*)d_in[2];
    const float* mask   = (const float*)d_in[3];
    float* acc = (float*)d_ws;
    float* out = (float*)d_out;

    hipMemsetAsync(d_ws, 0, NACC * sizeof(float), stream);
    ce_partial_kernel<<<2048, 256, 0, stream>>>(input, target, seg, mask, acc);
    ce_final_kernel<<<1, 64, 0, stream>>>(acc, out);
}